// Round 15
// baseline (816.532 us; speedup 1.0000x reference)
//
#include <hip/hip_runtime.h>
#include <math.h>

constexpr int N_ = 50000;
constexpr int E_ = 400000;
constexpr int H_ = 128;
constexpr int OUT_ = 64;
constexpr int B_ = 3;
constexpr int ITERS_ = 2;
constexpr float EPS_ = 0.01f;

typedef unsigned short u16;
typedef unsigned char u8;
typedef unsigned int u32;
typedef short v8s __attribute__((ext_vector_type(8)));
typedef float v4f __attribute__((ext_vector_type(4)));
typedef float v2f __attribute__((ext_vector_type(2)));

__device__ inline float b2f(u16 u) {
  union { unsigned int i; float f; } c;
  c.i = ((unsigned int)u) << 16;
  return c.f;
}
__device__ inline u16 f2b(float f) {
  union { float f; unsigned int u; } c;
  c.f = f;
  unsigned int r = c.u + 0x7fffu + ((c.u >> 16) & 1u);  // RNE
  return (u16)(r >> 16);
}
__device__ inline unsigned int pk(float a, float b) {
  return (unsigned int)f2b(a) | ((unsigned int)f2b(b) << 16);
}
__device__ inline v8s pack8(const float4 u, const float4 v) {
  v8s r;
  r[0] = (short)f2b(u.x); r[1] = (short)f2b(u.y);
  r[2] = (short)f2b(u.z); r[3] = (short)f2b(u.w);
  r[4] = (short)f2b(v.x); r[5] = (short)f2b(v.y);
  r[6] = (short)f2b(v.z); r[7] = (short)f2b(v.w);
  return r;
}

#if defined(__has_builtin)
#if __has_builtin(__builtin_nontemporal_load)
#define NT_LOAD(p) __builtin_nontemporal_load(p)
#endif
#endif
#ifndef NT_LOAD
#define NT_LOAD(p) (*(p))
#endif

// ---------------- fp4 e2m1 encode/decode (arithmetic, no builtins) ---------
// codes 0..7 -> {0, .5, 1, 1.5, 2, 3, 4, 6}; bit3 = sign.
__device__ inline float dec4(u32 nib) {
  const u32 e = (nib >> 1) & 3u, m = nib & 1u;
  u32 bits = ((126u + e) << 23) | ((e ? m : 0u) << 22);
  if ((nib & 7u) == 0u) bits = 0u;
  bits |= (nib & 8u) << 28;
  return __uint_as_float(bits);
}
__device__ inline u32 enc4(float y) {
  const u32 s = (__float_as_uint(y) >> 31) << 3;
  const float a = fabsf(y);
  const u32 c = (u32)(a >= 0.25f) + (a >= 0.75f) + (a >= 1.25f) +
                (a >= 1.75f) + (a >= 2.5f) + (a >= 3.5f) + (a >= 5.0f);
  return s | c;
}

// ---------------------------------------------------------------------------
// A-resident MFMA GEMM, B-prefetched, LDS-staged coalesced stores.
// Block = NW waves x 64 rows; per group g wave wv owns 32 cols.
// AF: 0 = bf16 A input, 1 = fp32 A input (packed to bf16 on the fly).
// OT: 0 bf16 (stride 2H B), 2 fp32 (stride OUT_*4), 3 fp4 (stride H/2 B —
//     staged as 1 code byte/channel, packed 2->1 at flush; r15 gather fix).
// ---------------------------------------------------------------------------
template <int CG, int NW, int AF, int OT, int A0, int A1, int A2, int A3>
__global__ __launch_bounds__(NW * 64, 1) void gemm_k(
    const void* __restrict__ X_, const u16* __restrict__ Wb,
    const float* __restrict__ bias, void* __restrict__ y0,
    void* __restrict__ y1, void* __restrict__ y2, void* __restrict__ y3) {
  constexpr int GW = NW * 32;
  constexpr int SES = (OT == 0) ? 2 : (OT == 2) ? 4 : 1;  // staged bytes/ch
  constexpr int SDATB = GW * SES;
  constexpr int ROWB = (SDATB <= 128) ? 144 : 288;
  constexpr int OUTB = (OT == 3) ? GW / 2 : GW * SES;     // output bytes/row
  constexpr int OSTRIDE =
      (OT == 0) ? H_ * 2 : (OT == 2) ? OUT_ * 4 : (OT == 3) ? H_ / 2 : H_;
  constexpr int NST = (CG > 1) ? 2 : 1;
  __shared__ u8 st[NST][64 * ROWB];

  const int lane = threadIdx.x & 63;
  const int wv = threadIdx.x >> 6;
  const int rowbase = blockIdx.x * 64;
  const int bn = lane & 15;
  const int kc = (lane >> 4) * 8;
  const int ncol = lane & 15;
  const int rsub = (lane >> 4) * 4;

  // hoist ALL A fragments once (reused by every col-group)
  v8s a[4][4];
#pragma unroll
  for (int rt = 0; rt < 4; ++rt) {
    int arow = rowbase + rt * 16 + bn;
    if (arow >= N_) arow = N_ - 1;
    if constexpr (AF == 0) {
      const u16* Xb = (const u16*)X_;
#pragma unroll
      for (int ks = 0; ks < 4; ++ks)
        a[rt][ks] = *(const v8s*)(Xb + (size_t)arow * H_ + ks * 32 + kc);
    } else {
      const float* Xf = (const float*)X_;
#pragma unroll
      for (int ks = 0; ks < 4; ++ks) {
        const float4 u =
            *(const float4*)(Xf + (size_t)arow * H_ + ks * 32 + kc);
        const float4 v =
            *(const float4*)(Xf + (size_t)arow * H_ + ks * 32 + kc + 4);
        a[rt][ks] = pack8(u, v);
      }
    }
  }

  v8s bf0[2][4], bf1[2][4];
#pragma unroll
  for (int ct = 0; ct < 2; ++ct) {
    const u16* wp = Wb + (size_t)(wv * 32 + ct * 16 + bn) * H_ + kc;
#pragma unroll
    for (int ks = 0; ks < 4; ++ks) bf0[ct][ks] = *(const v8s*)(wp + ks * 32);
  }

#pragma unroll
  for (int g = 0; g < CG; ++g) {
    v8s(*cur)[4] = (g & 1) ? bf1 : bf0;
    if (g + 1 < CG) {  // prefetch next group's B while computing this one
      v8s(*nxt)[4] = (g & 1) ? bf0 : bf1;
#pragma unroll
      for (int ct = 0; ct < 2; ++ct) {
        const u16* wp =
            Wb + (size_t)((g + 1) * GW + wv * 32 + ct * 16 + bn) * H_ + kc;
#pragma unroll
        for (int ks = 0; ks < 4; ++ks)
          nxt[ct][ks] = *(const v8s*)(wp + ks * 32);
      }
    }
    v4f acc[2][4];
#pragma unroll
    for (int ct = 0; ct < 2; ++ct)
#pragma unroll
      for (int rt = 0; rt < 4; ++rt) acc[ct][rt] = (v4f)0.f;
#pragma unroll
    for (int rt = 0; rt < 4; ++rt)
#pragma unroll
      for (int ct = 0; ct < 2; ++ct)
#pragma unroll
        for (int ks = 0; ks < 4; ++ks)
          acc[ct][rt] = __builtin_amdgcn_mfma_f32_16x16x32_bf16(
              a[rt][ks], cur[ct][ks], acc[ct][rt], 0, 0, 0);

    const int act = (g == 0) ? A0 : (g == 1) ? A1 : (g == 2) ? A2 : A3;
    u8* sg = st[g & (NST - 1)];
#pragma unroll
    for (int ct = 0; ct < 2; ++ct) {
      const int col = wv * 32 + ct * 16 + ncol;
      const float bv = bias[g * GW + col];
#pragma unroll
      for (int rt = 0; rt < 4; ++rt) {
#pragma unroll
        for (int i = 0; i < 4; ++i) {
          float yv = acc[ct][rt][i] + bv;
          if (act == 1) yv = fmaxf(yv, 0.f);
          if (act == 2) yv = tanhf(yv);
          u8* p = sg + (rt * 16 + rsub + i) * ROWB + col * SES;
          if (OT == 0) *(u16*)p = f2b(yv);
          else if (OT == 3) *p = (u8)enc4(yv);
          else *(float*)p = yv;
        }
      }
    }
    __syncthreads();
    void* yp = (g == 0) ? y0 : (g == 1) ? y1 : (g == 2) ? y2 : y3;
    if constexpr (OT == 3) {
      // pack 2 codes -> 1 byte during the coalesced flush
      for (int o = threadIdx.x * 16; o < 64 * OUTB; o += NW * 64 * 16) {
        const int row = o / OUTB;
        const int cb = o - row * OUTB;
        const int gr = rowbase + row;
        if (gr < N_) {
          const u8* sp = sg + row * ROWB + cb * 2;
          u32 ow[4];
#pragma unroll
          for (int q = 0; q < 4; ++q) {
            const u32 w0 = *(const u32*)(sp + q * 8);
            const u32 w1 = *(const u32*)(sp + q * 8 + 4);
            const u32 t0 = w0 | (w0 >> 4);
            const u32 t1 = w1 | (w1 >> 4);
            ow[q] = ((t0 & 0xFFu) | ((t0 >> 8) & 0xFF00u)) |
                    ((((t1 & 0xFFu) | ((t1 >> 8) & 0xFF00u))) << 16);
          }
          uint4 v4 = {ow[0], ow[1], ow[2], ow[3]};
          *(uint4*)((u8*)yp + (size_t)gr * OSTRIDE + cb) = v4;
        }
      }
    } else {
      for (int o = threadIdx.x * 16; o < 64 * OUTB; o += NW * 64 * 16) {
        const int row = o / OUTB;
        const int cb8 = o - row * OUTB;
        const int gr = rowbase + row;
        if (gr < N_)
          *(float4*)((u8*)yp + (size_t)gr * OSTRIDE + cb8) =
              *(const float4*)(sg + row * ROWB + cb8);
      }
    }
  }
}

// ---------------------------------------------------------------------------
// Fused MLP, all loads hoisted: 4 waves x 32 cols, 64 rows/block (bf16 io).
// ---------------------------------------------------------------------------
__global__ __launch_bounds__(256, 1) void mlp6_k(
    const u16* __restrict__ Xb, const u16* __restrict__ Wm1,
    const float* __restrict__ bm1, const u16* __restrict__ Wm2,
    const float* __restrict__ bm2, u16* __restrict__ Yb) {
  __shared__ u16 tmp[64][144];
  const int lane = threadIdx.x & 63;
  const int wv = threadIdx.x >> 6;
  const int rowbase = blockIdx.x * 64;
  const int cb = wv * 32;
  const int bn = lane & 15;
  const int kc = (lane >> 4) * 8;
  const int ncol = lane & 15;
  const int rsub = (lane >> 4) * 4;

  v8s a[4][4];
#pragma unroll
  for (int rt = 0; rt < 4; ++rt) {
    int arow = rowbase + rt * 16 + bn;
    if (arow >= N_) arow = N_ - 1;
#pragma unroll
    for (int ks = 0; ks < 4; ++ks)
      a[rt][ks] = *(const v8s*)(Xb + (size_t)arow * H_ + ks * 32 + kc);
  }
  v8s bfm1[2][4], bfm2[2][4];
#pragma unroll
  for (int ct = 0; ct < 2; ++ct) {
    const u16* wp1 = Wm1 + (size_t)(cb + ct * 16 + bn) * H_ + kc;
    const u16* wp2 = Wm2 + (size_t)(cb + ct * 16 + bn) * H_ + kc;
#pragma unroll
    for (int ks = 0; ks < 4; ++ks) {
      bfm1[ct][ks] = *(const v8s*)(wp1 + ks * 32);
      bfm2[ct][ks] = *(const v8s*)(wp2 + ks * 32);
    }
  }

  v4f acc[2][4];
#pragma unroll
  for (int ct = 0; ct < 2; ++ct)
#pragma unroll
    for (int rt = 0; rt < 4; ++rt) acc[ct][rt] = (v4f)0.f;
#pragma unroll
  for (int rt = 0; rt < 4; ++rt)
#pragma unroll
    for (int ct = 0; ct < 2; ++ct)
#pragma unroll
      for (int ks = 0; ks < 4; ++ks)
        acc[ct][rt] = __builtin_amdgcn_mfma_f32_16x16x32_bf16(
            a[rt][ks], bfm1[ct][ks], acc[ct][rt], 0, 0, 0);
#pragma unroll
  for (int ct = 0; ct < 2; ++ct) {
    const float bv = bm1[cb + ct * 16 + ncol];
#pragma unroll
    for (int rt = 0; rt < 4; ++rt)
#pragma unroll
      for (int i = 0; i < 4; ++i)
        tmp[rt * 16 + rsub + i][cb + ct * 16 + ncol] =
            f2b(tanhf(acc[ct][rt][i] + bv));
  }
  __syncthreads();

#pragma unroll
  for (int rt = 0; rt < 4; ++rt) {
    const int arow = rt * 16 + bn;
#pragma unroll
    for (int ks = 0; ks < 4; ++ks)
      a[rt][ks] = *(const v8s*)&tmp[arow][ks * 32 + kc];
  }
  __syncthreads();  // all layer-2 A reads done before tmp is overwritten
#pragma unroll
  for (int ct = 0; ct < 2; ++ct)
#pragma unroll
    for (int rt = 0; rt < 4; ++rt) acc[ct][rt] = (v4f)0.f;
#pragma unroll
  for (int rt = 0; rt < 4; ++rt)
#pragma unroll
    for (int ct = 0; ct < 2; ++ct)
#pragma unroll
      for (int ks = 0; ks < 4; ++ks)
        acc[ct][rt] = __builtin_amdgcn_mfma_f32_16x16x32_bf16(
            a[rt][ks], bfm2[ct][ks], acc[ct][rt], 0, 0, 0);
#pragma unroll
  for (int ct = 0; ct < 2; ++ct) {
    const float bv = bm2[cb + ct * 16 + ncol];
#pragma unroll
    for (int rt = 0; rt < 4; ++rt)
#pragma unroll
      for (int i = 0; i < 4; ++i)
        tmp[rt * 16 + rsub + i][cb + ct * 16 + ncol] =
            f2b(acc[ct][rt][i] + bv);
  }
  __syncthreads();
  for (int o = threadIdx.x * 16; o < 64 * 256; o += 256 * 16) {
    const int row = o >> 8;
    const int cb8 = o & 255;
    const int gr = rowbase + row;
    if (gr < N_)
      *(float4*)((u8*)Yb + (size_t)gr * (H_ * 2) + cb8) =
          *(const float4*)((const u8*)&tmp[row][0] + cb8);
  }
}

// ---------------------------------------------------------------------------
// Weight pack + bias pack (merged).
// ---------------------------------------------------------------------------
constexpr int WB_EMB = 0;                 // 128x128
constexpr int WB_RO = 16384;              // 64x128
constexpr int WB_BLK = 24576;             // per block: 98304
constexpr int WB_TOTAL = 24576 + 3 * 98304;  // 319488
constexpr int CONV_TOT = WB_TOTAL + 3 * 512 + 3 * 256;

__global__ void convall_k(const float* __restrict__ emb_w,
                          const float* __restrict__ ro_w,
                          const float* __restrict__ er_w1,
                          const float* __restrict__ lap_w,
                          const float* __restrict__ diss_w,
                          const float* __restrict__ mlp_w1,
                          const float* __restrict__ mlp_w2,
                          const float* __restrict__ er_b1,
                          const float* __restrict__ diss_b,
                          u16* __restrict__ wb, float* __restrict__ bp512,
                          float* __restrict__ bfd) {
  const int idx = blockIdx.x * 256 + threadIdx.x;
  if (idx >= CONV_TOT) return;
  if (idx >= WB_TOTAL) {
    int t2 = idx - WB_TOTAL;
    if (t2 < 3 * 512) {
      const int b = t2 >> 9, t = t2 & 511;
      float v = 0.f;
      if (t < 128) v = er_b1[b * 128 + t];
      else if (t >= 384) v = diss_b[b * 128 + (t - 384)];
      bp512[b * 512 + t] = v;
    } else {
      t2 -= 3 * 512;
      const int b = t2 >> 8, t = t2 & 255;
      bfd[b * 256 + t] = (t < 128) ? 0.f : diss_b[b * 128 + (t - 128)];
    }
    return;
  }
  const float* src;
  size_t soff;
  if (idx < 16384) {
    src = emb_w; soff = idx;
  } else if (idx < 24576) {
    src = ro_w; soff = idx - 16384;
  } else {
    int t = idx - 24576;
    const int b = t / 98304;
    t -= b * 98304;
    if (t < 32768) {  // Wp: rows<128 -> er_w1 cols 0-127; rows>=128 -> cols 128-255
      const int r = t >> 7, c = t & 127;
      src = er_w1 + (size_t)b * 32768;
      soff = (r < 128) ? ((size_t)r * 256 + c) : ((size_t)(r - 128) * 256 + 128 + c);
    } else if (t < 65536) {  // Wfd: rows<128 lap, rows>=128 diss
      const int u = t - 32768;
      if (u < 16384) { src = lap_w + (size_t)b * 16384; soff = u; }
      else { src = diss_w + (size_t)b * 16384; soff = u - 16384; }
    } else if (t < 81920) {
      src = mlp_w1 + (size_t)b * 16384; soff = t - 65536;
    } else {
      src = mlp_w2 + (size_t)b * 16384; soff = t - 81920;
    }
  }
  wb[idx] = f2b(src[soff]);
}

// ---------------------------------------------------------------------------
// Edge resistance, dst-sorted, fp4 P tables (64 B rows = ONE cache line per
// gather; tables L2-resident). 2 edges per 16-lane group; lane holds 8 ch
// (one dword of 8 nibbles).  r[i] = |w2 . relu(P1[ss]+P2[ds]) + b2|.
// ---------------------------------------------------------------------------
__device__ inline float edot8(u32 a, u32 c, const float* w) {
  float s = 0.f;
#pragma unroll
  for (int j = 0; j < 8; ++j) {
    const float av = dec4((a >> (4 * j)) & 0xFu);
    const float cv = dec4((c >> (4 * j)) & 0xFu);
    s = fmaf(fmaxf(av + cv, 0.f), w[j], s);
  }
  return s;
}

__global__ __launch_bounds__(256) void edge_r_k(
    const u32* __restrict__ P1, const u32* __restrict__ P2,
    const int* __restrict__ ss, const int* __restrict__ ds,
    const float* __restrict__ w2, const float* __restrict__ b2,
    float* __restrict__ r_out, float* __restrict__ deg) {
  const int tid = threadIdx.x;
  const int sub = tid & 15;
  const size_t e0 = (size_t)blockIdx.x * 32 + (tid >> 4) * 2;
  const size_t e1 = e0 + 1;
  float w[8];
  *(float4*)&w[0] = *(const float4*)(w2 + sub * 8);
  *(float4*)&w[4] = *(const float4*)(w2 + sub * 8 + 4);
  const int s0 = ss[e0], s1 = ss[e1];
  const int d0 = ds[e0], d1 = ds[e1];
  const u32 av0 = P1[(size_t)s0 * 16 + sub];
  const u32 cv0 = P2[(size_t)d0 * 16 + sub];
  const u32 av1 = P1[(size_t)s1 * 16 + sub];
  const u32 cv1 = P2[(size_t)d1 * 16 + sub];
  float sum0 = edot8(av0, cv0, w);
  float sum1 = edot8(av1, cv1, w);
#pragma unroll
  for (int off = 8; off > 0; off >>= 1) {
    sum0 += __shfl_xor(sum0, off);
    sum1 += __shfl_xor(sum1, off);
  }
  if (sub == 0) {
    const float rv0 = fabsf(sum0 + b2[0]);
    const float rv1 = fabsf(sum1 + b2[0]);
    r_out[e0] = rv0;
    r_out[e1] = rv1;
    atomicAdd(&deg[s0], rv0);
    atomicAdd(&deg[s1], rv1);
  }
}

// ---------------------------------------------------------------------------
// CSR build (by dst): hist -> parallel scan -> sorted src/dst arrays.
// ---------------------------------------------------------------------------
constexpr int NSC = (N_ + 1023) / 1024;  // 49

__global__ void hist_k(const int* __restrict__ dst, int* __restrict__ cnt) {
  const int e = blockIdx.x * 256 + threadIdx.x;
  if (e < E_) atomicAdd(&cnt[dst[e]], 1);
}

__global__ __launch_bounds__(1024) void partial_k(const int* __restrict__ cnt,
                                                  int* __restrict__ psum) {
  __shared__ int sm[1024];
  const int tid = threadIdx.x;
  const int i = blockIdx.x * 1024 + tid;
  sm[tid] = (i < N_) ? cnt[i] : 0;
  __syncthreads();
  for (int off = 512; off > 0; off >>= 1) {
    if (tid < off) sm[tid] += sm[tid + off];
    __syncthreads();
  }
  if (tid == 0) psum[blockIdx.x] = sm[0];
}

__global__ __launch_bounds__(64) void scanp_k(int* __restrict__ psum) {
  const int tid = threadIdx.x;
  int v = (tid < NSC) ? psum[tid] : 0;
  const int orig = v;
#pragma unroll
  for (int off = 1; off < 64; off <<= 1) {
    const int u = __shfl_up(v, off);
    if (tid >= off) v += u;
  }
  if (tid < NSC) psum[tid] = v - orig;  // exclusive
}

__global__ __launch_bounds__(1024) void rowptr_k(const int* __restrict__ cnt,
                                                 const int* __restrict__ psum,
                                                 int* __restrict__ rowptr,
                                                 int* __restrict__ cursor) {
  __shared__ int sm[1024];
  const int tid = threadIdx.x;
  const int i = blockIdx.x * 1024 + tid;
  const int orig = (i < N_) ? cnt[i] : 0;
  sm[tid] = orig;
  __syncthreads();
  for (int off = 1; off < 1024; off <<= 1) {
    const int mine = sm[tid];
    const int u = (tid >= off) ? sm[tid - off] : 0;
    __syncthreads();
    sm[tid] = mine + u;
    __syncthreads();
  }
  const int excl = sm[tid] - orig + psum[blockIdx.x];
  if (i < N_) {
    rowptr[i] = excl;
    cursor[i] = excl;
  }
  if (i == 0) rowptr[N_] = E_;
}

__global__ void permute_k(const int* __restrict__ src,
                          const int* __restrict__ dst, int* __restrict__ cursor,
                          int* __restrict__ ss, int* __restrict__ ds) {
  const int e = blockIdx.x * 256 + threadIdx.x;
  if (e < E_) {
    const int d = dst[e];
    const int p = atomicAdd(&cursor[d], 1);
    ss[p] = src[e];
    ds[p] = d;
  }
}

// ---------------------------------------------------------------------------
// Fused aggregate + update. f/diss fp4 (64 B rows: one line per gather,
// table L2-resident — r15 random-line fix); xb/vb bf16.
// One wave per node; lane reads 1 byte = its 2 channels. 8-deep volley.
// ---------------------------------------------------------------------------
template <bool FIRST>
__global__ __launch_bounds__(256) void agg_update_k(
    unsigned int* __restrict__ xb, unsigned int* __restrict__ vb,
    const u8* __restrict__ f4, const u8* __restrict__ diss4,
    const float* __restrict__ deg, const float* __restrict__ r,
    const int* __restrict__ ss, const int* __restrict__ rowptr) {
  const int wid = threadIdx.x >> 6;
  const int lane = threadIdx.x & 63;
  const int n = blockIdx.x * 4 + wid;
  const int beg = rowptr[n];
  const int end = rowptr[n + 1];
  float ax = 0.f, ay = 0.f;
  for (int i = beg; i < end; i += 8) {
    int ei[8];
    float rr[8];
    u8 fv[8];
#pragma unroll
    for (int k = 0; k < 8; ++k) ei[k] = (i + k < end) ? i + k : i;
#pragma unroll
    for (int k = 0; k < 8; ++k) {
      const int s = NT_LOAD(ss + ei[k]);
      fv[k] = f4[(size_t)s * 64 + lane];
    }
#pragma unroll
    for (int k = 0; k < 8; ++k)
      rr[k] = (i + k < end) ? NT_LOAD(r + ei[k]) : 0.f;
#pragma unroll
    for (int k = 0; k < 8; ++k) {
      ax = fmaf(rr[k], dec4(fv[k] & 0xFu), ax);
      ay = fmaf(rr[k], dec4(fv[k] >> 4), ay);
    }
  }
  const size_t idx = (size_t)n * 64 + lane;
  const u8 fnb = f4[idx];
  const float dg = deg[n];
  const float cx = dg * dec4(fnb & 0xFu) - ax;
  const float cy = dg * dec4(fnb >> 4) - ay;
  float vx, vy;
  if (FIRST) {
    vx = -EPS_ * cx;
    vy = -EPS_ * cy;
    vb[idx] = pk(vx, vy);
  } else {
    const u8 db = diss4[idx];
    const unsigned int vv = vb[idx];
    vx = b2f((u16)(vv & 0xffffu));
    vy = b2f((u16)(vv >> 16));
    vx = vx - EPS_ * (cx + dec4(db & 0xFu) * vx);
    vy = vy - EPS_ * (cy + dec4(db >> 4) * vy);
  }
  const unsigned int xv = xb[idx];
  const float nx = b2f((u16)(xv & 0xffffu)) + EPS_ * vx;
  const float ny = b2f((u16)(xv >> 16)) + EPS_ * vy;
  xb[idx] = pk(nx, ny);
}

extern "C" void kernel_launch(void* const* d_in, const int* in_sizes, int n_in,
                              void* d_out, int out_size, void* d_ws,
                              size_t ws_size, hipStream_t stream) {
  const float* x_in = (const float*)d_in[0];
  const int* ei = (const int*)d_in[1];
  const int* src = ei;
  const int* dst = ei + E_;
  const float* emb_w = (const float*)d_in[2];
  const float* emb_b = (const float*)d_in[3];
  const float* lap_w = (const float*)d_in[4];
  const float* er_w1 = (const float*)d_in[5];
  const float* er_b1 = (const float*)d_in[6];
  const float* er_w2 = (const float*)d_in[7];
  const float* er_b2 = (const float*)d_in[8];
  const float* diss_w = (const float*)d_in[9];
  const float* diss_b = (const float*)d_in[10];
  const float* mlp_w1 = (const float*)d_in[11];
  const float* mlp_b1 = (const float*)d_in[12];
  const float* mlp_w2 = (const float*)d_in[13];
  const float* mlp_b2 = (const float*)d_in[14];
  const float* ro_w = (const float*)d_in[15];
  const float* ro_b = (const float*)d_in[16];
  float* out = (float*)d_out;

  // workspace layout
  const size_t NF = (size_t)N_ * H_;
  const size_t NH = NF / 2;         // bytes per fp4 table (N * 64)
  u16* xb = (u16*)d_ws;             // NF bf16 (x state)
  u16* vb = xb + NF;                // NF bf16 (v)
  u8* P1 = (u8*)(vb + NF);          // NH fp4
  u8* P2 = P1 + NH;                 // NH fp4
  u8* F4 = P2 + NH;                 // NH fp4
  u8* D4 = F4 + NH;                 // NH fp4
  float* r = (float*)(D4 + NH);     // E (dst-sorted)
  float* deg = r + E_;              // N
  int* rowptr = (int*)(deg + N_);   // N+1
  int* cursor = rowptr + (N_ + 1);  // N
  int* ss = cursor + N_;            // E (src, dst-sorted)
  int* ds = ss + E_;                // E (dst, dst-sorted)
  int* psum = ds + E_;              // NSC
  u16* wb = (u16*)(psum + NSC);     // WB_TOTAL bf16
  float* bp512 = (float*)(wb + WB_TOTAL + (WB_TOTAL & 1));  // 3*512
  float* bfd = bp512 + 3 * 512;     // 3*256

  const int g64 = (N_ + 63) / 64;  // 782
  const int e_grid = (E_ + 255) / 256;

  // pack weights + biases (merged)
  convall_k<<<(CONV_TOT + 255) / 256, 256, 0, stream>>>(
      emb_w, ro_w, er_w1, lap_w, diss_w, mlp_w1, mlp_w2, er_b1, diss_b, wb,
      bp512, bfd);

  // CSR by dst (topology fixed for whole launch)
  hipMemsetAsync(cursor, 0, N_ * sizeof(int), stream);
  hist_k<<<e_grid, 256, 0, stream>>>(dst, cursor);
  partial_k<<<NSC, 1024, 0, stream>>>(cursor, psum);
  scanp_k<<<1, 64, 0, stream>>>(psum);
  rowptr_k<<<NSC, 1024, 0, stream>>>(cursor, psum, rowptr, cursor);
  permute_k<<<e_grid, 256, 0, stream>>>(src, dst, cursor, ss, ds);

  // xb = emb(x_in)  (fp32 A input, bf16 out, 1 group)
  gemm_k<1, 4, 1, 0, 0, 0, 0, 0><<<g64, 256, 0, stream>>>(
      x_in, wb + WB_EMB, emb_b, xb, nullptr, nullptr, nullptr);

  for (int b = 0; b < B_; ++b) {
    const u16* Wp = wb + WB_BLK + (size_t)b * 98304;   // 256 rows (er split)
    const u16* Wfd = Wp + 32768;                       // 256 rows (lap;diss)
    const u16* Wm1 = Wfd + 32768;
    const u16* Wm2 = Wm1 + 16384;
    const float* b2 = er_b2 + b;
    const float* w2 = er_w2 + (size_t)b * H_;

    // Merged it=0 GEMM: [P1 | P2 | f | diss] = xb @ [Wp;Wfd]^T (4 groups,
    // all fp4 out).
    gemm_k<4, 4, 0, 3, 0, 0, 0, 1><<<g64, 256, 0, stream>>>(
        xb, Wp, bp512 + b * 512, P1, P2, F4, D4);
    hipMemsetAsync(deg, 0, N_ * sizeof(float), stream);
    edge_r_k<<<E_ / 32, 256, 0, stream>>>((const u32*)P1, (const u32*)P2, ss,
                                          ds, w2, b2, r, deg);

    // it = 0 (uses F4/D4 from merged GEMM)
    agg_update_k<true><<<N_ / 4, 256, 0, stream>>>(
        (unsigned int*)xb, (unsigned int*)vb, F4, D4, deg, r, ss, rowptr);
    // it = 1: recompute f/diss from updated xb (2 groups, fp4 out)
    gemm_k<2, 4, 0, 3, 0, 1, 0, 0><<<g64, 256, 0, stream>>>(
        xb, Wfd, bfd + b * 256, F4, D4, nullptr, nullptr);
    agg_update_k<false><<<N_ / 4, 256, 0, stream>>>(
        (unsigned int*)xb, (unsigned int*)vb, F4, D4, deg, r, ss, rowptr);

    // xb = tanh(xb@Wm1^T + bm1) @ Wm2^T + bm2
    mlp6_k<<<g64, 256, 0, stream>>>(xb, Wm1, mlp_b1 + b * H_, Wm2,
                                    mlp_b2 + b * H_, xb);
  }
  gemm_k<1, 2, 0, 2, 0, 0, 0, 0><<<g64, 128, 0, stream>>>(
      xb, wb + WB_RO, ro_b, out, nullptr, nullptr, nullptr);
}

// Round 16
// 596.581 us; speedup vs baseline: 1.3687x; 1.3687x over previous
//
#include <hip/hip_runtime.h>
#include <math.h>

constexpr int N_ = 50000;
constexpr int E_ = 400000;
constexpr int H_ = 128;
constexpr int OUT_ = 64;
constexpr int B_ = 3;
constexpr int ITERS_ = 2;
constexpr float EPS_ = 0.01f;

typedef unsigned short u16;
typedef unsigned char u8;
typedef short v8s __attribute__((ext_vector_type(8)));
typedef float v4f __attribute__((ext_vector_type(4)));
typedef float v2f __attribute__((ext_vector_type(2)));

__device__ inline float b2f(u16 u) {
  union { unsigned int i; float f; } c;
  c.i = ((unsigned int)u) << 16;
  return c.f;
}
__device__ inline u16 f2b(float f) {
  union { float f; unsigned int u; } c;
  c.f = f;
  unsigned int r = c.u + 0x7fffu + ((c.u >> 16) & 1u);  // RNE
  return (u16)(r >> 16);
}
__device__ inline unsigned int pk(float a, float b) {
  return (unsigned int)f2b(a) | ((unsigned int)f2b(b) << 16);
}
__device__ inline v8s pack8(const float4 u, const float4 v) {
  v8s r;
  r[0] = (short)f2b(u.x); r[1] = (short)f2b(u.y);
  r[2] = (short)f2b(u.z); r[3] = (short)f2b(u.w);
  r[4] = (short)f2b(v.x); r[5] = (short)f2b(v.y);
  r[6] = (short)f2b(v.z); r[7] = (short)f2b(v.w);
  return r;
}

#if defined(__has_builtin)
#if __has_builtin(__builtin_nontemporal_load)
#define NT_LOAD(p) __builtin_nontemporal_load(p)
#endif
#endif
#ifndef NT_LOAD
#define NT_LOAD(p) (*(p))
#endif

// ---------------- fp8 e4m3 encode/decode (HW cvt if available) -------------
#if defined(__has_builtin)
#if __has_builtin(__builtin_amdgcn_cvt_pk_f32_fp8) && \
    __has_builtin(__builtin_amdgcn_cvt_pk_fp8_f32)
#define HW_FP8 1
#endif
#endif

#ifdef HW_FP8
__device__ inline v2f dec_lo(unsigned int v) {
  return __builtin_amdgcn_cvt_pk_f32_fp8(v, false);
}
__device__ inline v2f dec_hi(unsigned int v) {
  return __builtin_amdgcn_cvt_pk_f32_fp8(v, true);
}
__device__ inline u8 enc1(float x) {
  return (u8)(__builtin_amdgcn_cvt_pk_fp8_f32(x, x, 0, false) & 0xff);
}
#else
__device__ inline float fp8_dec1(u8 v) {
  const unsigned int s = v >> 7, e = (v >> 3) & 15, m = v & 7;
  float mag = e ? __uint_as_float(((e + 120u) << 23) | (m << 20))
                : (float)m * 0.001953125f;
  return s ? -mag : mag;
}
__device__ inline v2f dec_lo(unsigned int v) {
  v2f r;
  r.x = fp8_dec1((u8)(v & 0xff));
  r.y = fp8_dec1((u8)((v >> 8) & 0xff));
  return r;
}
__device__ inline v2f dec_hi(unsigned int v) {
  v2f r;
  r.x = fp8_dec1((u8)((v >> 16) & 0xff));
  r.y = fp8_dec1((u8)((v >> 24) & 0xff));
  return r;
}
__device__ inline u8 enc1(float x) {
  union { float f; unsigned int u; } c;
  c.f = x;
  const unsigned int sgn = (c.u >> 31) << 7;
  float af = fabsf(x);
  if (af >= 448.f) return (u8)(sgn | 0x7e);
  if (af < 0.015625f) {
    int m = (int)rintf(af * 512.f);
    if (m > 7) return (u8)(sgn | 0x08);
    return (u8)(sgn | m);
  }
  unsigned int u = c.u & 0x7fffffffu;
  u += 0x7ffffu + ((u >> 20) & 1u);
  unsigned int m3 = (u >> 20) & 7;
  int e8 = (int)(u >> 23) - 120;
  if (e8 >= 15 && m3 >= 7) return (u8)(sgn | 0x7e);
  if (e8 <= 0) {
    int m = (int)rintf(af * 512.f);
    if (m > 7) m = 7;
    return (u8)(sgn | m);
  }
  return (u8)(sgn | ((unsigned)e8 << 3) | m3);
}
#endif

// ---------------------------------------------------------------------------
// A-resident MFMA GEMM, B-prefetched, LDS-staged coalesced stores.
// Block = NW waves x 64 rows; per group g wave wv owns 32 cols.
// AF: 0 = bf16 A input, 1 = fp32 A input (packed to bf16 on the fly).
// OT: 0 bf16 (stride H), 1 fp8 (stride H), 2 fp32 (stride OUT_).
// ---------------------------------------------------------------------------
template <int CG, int NW, int AF, int OT, int A0, int A1, int A2, int A3>
__global__ __launch_bounds__(NW * 64, 1) void gemm_k(
    const void* __restrict__ X_, const u16* __restrict__ Wb,
    const float* __restrict__ bias, void* __restrict__ y0,
    void* __restrict__ y1, void* __restrict__ y2, void* __restrict__ y3) {
  constexpr int GW = NW * 32;
  constexpr int ES = (OT == 0) ? 2 : (OT == 1) ? 1 : 4;
  constexpr int DATB = GW * ES;
  constexpr int ROWB = (DATB <= 128) ? 144 : 288;
  constexpr int OSTRIDE = (OT == 0) ? H_ * 2 : (OT == 1) ? H_ : OUT_ * 4;
  constexpr int NST = (CG > 1) ? 2 : 1;
  __shared__ u8 st[NST][64 * ROWB];

  const int lane = threadIdx.x & 63;
  const int wv = threadIdx.x >> 6;
  const int rowbase = blockIdx.x * 64;
  const int bn = lane & 15;
  const int kc = (lane >> 4) * 8;
  const int ncol = lane & 15;
  const int rsub = (lane >> 4) * 4;

  // hoist ALL A fragments once (reused by every col-group)
  v8s a[4][4];
#pragma unroll
  for (int rt = 0; rt < 4; ++rt) {
    int arow = rowbase + rt * 16 + bn;
    if (arow >= N_) arow = N_ - 1;
    if constexpr (AF == 0) {
      const u16* Xb = (const u16*)X_;
#pragma unroll
      for (int ks = 0; ks < 4; ++ks)
        a[rt][ks] = *(const v8s*)(Xb + (size_t)arow * H_ + ks * 32 + kc);
    } else {
      const float* Xf = (const float*)X_;
#pragma unroll
      for (int ks = 0; ks < 4; ++ks) {
        const float4 u =
            *(const float4*)(Xf + (size_t)arow * H_ + ks * 32 + kc);
        const float4 v =
            *(const float4*)(Xf + (size_t)arow * H_ + ks * 32 + kc + 4);
        a[rt][ks] = pack8(u, v);
      }
    }
  }

  v8s bf0[2][4], bf1[2][4];
#pragma unroll
  for (int ct = 0; ct < 2; ++ct) {
    const u16* wp = Wb + (size_t)(wv * 32 + ct * 16 + bn) * H_ + kc;
#pragma unroll
    for (int ks = 0; ks < 4; ++ks) bf0[ct][ks] = *(const v8s*)(wp + ks * 32);
  }

#pragma unroll
  for (int g = 0; g < CG; ++g) {
    v8s(*cur)[4] = (g & 1) ? bf1 : bf0;
    if (g + 1 < CG) {  // prefetch next group's B while computing this one
      v8s(*nxt)[4] = (g & 1) ? bf0 : bf1;
#pragma unroll
      for (int ct = 0; ct < 2; ++ct) {
        const u16* wp =
            Wb + (size_t)((g + 1) * GW + wv * 32 + ct * 16 + bn) * H_ + kc;
#pragma unroll
        for (int ks = 0; ks < 4; ++ks)
          nxt[ct][ks] = *(const v8s*)(wp + ks * 32);
      }
    }
    v4f acc[2][4];
#pragma unroll
    for (int ct = 0; ct < 2; ++ct)
#pragma unroll
      for (int rt = 0; rt < 4; ++rt) acc[ct][rt] = (v4f)0.f;
#pragma unroll
    for (int rt = 0; rt < 4; ++rt)
#pragma unroll
      for (int ct = 0; ct < 2; ++ct)
#pragma unroll
        for (int ks = 0; ks < 4; ++ks)
          acc[ct][rt] = __builtin_amdgcn_mfma_f32_16x16x32_bf16(
              a[rt][ks], cur[ct][ks], acc[ct][rt], 0, 0, 0);

    const int act = (g == 0) ? A0 : (g == 1) ? A1 : (g == 2) ? A2 : A3;
    u8* sg = st[g & (NST - 1)];
#pragma unroll
    for (int ct = 0; ct < 2; ++ct) {
      const int col = wv * 32 + ct * 16 + ncol;
      const float bv = bias[g * GW + col];
#pragma unroll
      for (int rt = 0; rt < 4; ++rt) {
#pragma unroll
        for (int i = 0; i < 4; ++i) {
          float yv = acc[ct][rt][i] + bv;
          if (act == 1) yv = fmaxf(yv, 0.f);
          if (act == 2) yv = tanhf(yv);
          u8* p = sg + (rt * 16 + rsub + i) * ROWB + col * ES;
          if (OT == 0) *(u16*)p = f2b(yv);
          else if (OT == 1) *p = enc1(yv);
          else *(float*)p = yv;
        }
      }
    }
    __syncthreads();
    void* yp = (g == 0) ? y0 : (g == 1) ? y1 : (g == 2) ? y2 : y3;
    for (int o = threadIdx.x * 16; o < 64 * DATB; o += NW * 64 * 16) {
      const int row = o / DATB;
      const int cb8 = o - row * DATB;
      const int gr = rowbase + row;
      if (gr < N_)
        *(float4*)((u8*)yp + (size_t)gr * OSTRIDE + cb8) =
            *(const float4*)(sg + row * ROWB + cb8);
    }
  }
}

// ---------------------------------------------------------------------------
// Fused MLP, all loads hoisted: 4 waves x 32 cols, 64 rows/block.
// ---------------------------------------------------------------------------
__global__ __launch_bounds__(256, 1) void mlp6_k(
    const u16* __restrict__ Xb, const u16* __restrict__ Wm1,
    const float* __restrict__ bm1, const u16* __restrict__ Wm2,
    const float* __restrict__ bm2, u16* __restrict__ Yb) {
  __shared__ u16 tmp[64][144];
  const int lane = threadIdx.x & 63;
  const int wv = threadIdx.x >> 6;
  const int rowbase = blockIdx.x * 64;
  const int cb = wv * 32;
  const int bn = lane & 15;
  const int kc = (lane >> 4) * 8;
  const int ncol = lane & 15;
  const int rsub = (lane >> 4) * 4;

  v8s a[4][4];
#pragma unroll
  for (int rt = 0; rt < 4; ++rt) {
    int arow = rowbase + rt * 16 + bn;
    if (arow >= N_) arow = N_ - 1;
#pragma unroll
    for (int ks = 0; ks < 4; ++ks)
      a[rt][ks] = *(const v8s*)(Xb + (size_t)arow * H_ + ks * 32 + kc);
  }
  v8s bfm1[2][4], bfm2[2][4];
#pragma unroll
  for (int ct = 0; ct < 2; ++ct) {
    const u16* wp1 = Wm1 + (size_t)(cb + ct * 16 + bn) * H_ + kc;
    const u16* wp2 = Wm2 + (size_t)(cb + ct * 16 + bn) * H_ + kc;
#pragma unroll
    for (int ks = 0; ks < 4; ++ks) {
      bfm1[ct][ks] = *(const v8s*)(wp1 + ks * 32);
      bfm2[ct][ks] = *(const v8s*)(wp2 + ks * 32);
    }
  }

  v4f acc[2][4];
#pragma unroll
  for (int ct = 0; ct < 2; ++ct)
#pragma unroll
    for (int rt = 0; rt < 4; ++rt) acc[ct][rt] = (v4f)0.f;
#pragma unroll
  for (int rt = 0; rt < 4; ++rt)
#pragma unroll
    for (int ct = 0; ct < 2; ++ct)
#pragma unroll
      for (int ks = 0; ks < 4; ++ks)
        acc[ct][rt] = __builtin_amdgcn_mfma_f32_16x16x32_bf16(
            a[rt][ks], bfm1[ct][ks], acc[ct][rt], 0, 0, 0);
#pragma unroll
  for (int ct = 0; ct < 2; ++ct) {
    const float bv = bm1[cb + ct * 16 + ncol];
#pragma unroll
    for (int rt = 0; rt < 4; ++rt)
#pragma unroll
      for (int i = 0; i < 4; ++i)
        tmp[rt * 16 + rsub + i][cb + ct * 16 + ncol] =
            f2b(tanhf(acc[ct][rt][i] + bv));
  }
  __syncthreads();

#pragma unroll
  for (int rt = 0; rt < 4; ++rt) {
    const int arow = rt * 16 + bn;
#pragma unroll
    for (int ks = 0; ks < 4; ++ks)
      a[rt][ks] = *(const v8s*)&tmp[arow][ks * 32 + kc];
  }
  __syncthreads();  // all layer-2 A reads done before tmp is overwritten
#pragma unroll
  for (int ct = 0; ct < 2; ++ct)
#pragma unroll
    for (int rt = 0; rt < 4; ++rt) acc[ct][rt] = (v4f)0.f;
#pragma unroll
  for (int rt = 0; rt < 4; ++rt)
#pragma unroll
    for (int ct = 0; ct < 2; ++ct)
#pragma unroll
      for (int ks = 0; ks < 4; ++ks)
        acc[ct][rt] = __builtin_amdgcn_mfma_f32_16x16x32_bf16(
            a[rt][ks], bfm2[ct][ks], acc[ct][rt], 0, 0, 0);
#pragma unroll
  for (int ct = 0; ct < 2; ++ct) {
    const float bv = bm2[cb + ct * 16 + ncol];
#pragma unroll
    for (int rt = 0; rt < 4; ++rt)
#pragma unroll
      for (int i = 0; i < 4; ++i)
        tmp[rt * 16 + rsub + i][cb + ct * 16 + ncol] =
            f2b(acc[ct][rt][i] + bv);
  }
  __syncthreads();
  for (int o = threadIdx.x * 16; o < 64 * 256; o += 256 * 16) {
    const int row = o >> 8;
    const int cb8 = o & 255;
    const int gr = rowbase + row;
    if (gr < N_)
      *(float4*)((u8*)Yb + (size_t)gr * (H_ * 2) + cb8) =
          *(const float4*)((const u8*)&tmp[row][0] + cb8);
  }
}

// ---------------------------------------------------------------------------
// Weight pack + bias pack (merged).
// ---------------------------------------------------------------------------
constexpr int WB_EMB = 0;                 // 128x128
constexpr int WB_RO = 16384;              // 64x128
constexpr int WB_BLK = 24576;             // per block: 98304
constexpr int WB_TOTAL = 24576 + 3 * 98304;  // 319488
constexpr int CONV_TOT = WB_TOTAL + 3 * 512 + 3 * 256;

__global__ void convall_k(const float* __restrict__ emb_w,
                          const float* __restrict__ ro_w,
                          const float* __restrict__ er_w1,
                          const float* __restrict__ lap_w,
                          const float* __restrict__ diss_w,
                          const float* __restrict__ mlp_w1,
                          const float* __restrict__ mlp_w2,
                          const float* __restrict__ er_b1,
                          const float* __restrict__ diss_b,
                          u16* __restrict__ wb, float* __restrict__ bp512,
                          float* __restrict__ bfd) {
  const int idx = blockIdx.x * 256 + threadIdx.x;
  if (idx >= CONV_TOT) return;
  if (idx >= WB_TOTAL) {
    int t2 = idx - WB_TOTAL;
    if (t2 < 3 * 512) {
      const int b = t2 >> 9, t = t2 & 511;
      float v = 0.f;
      if (t < 128) v = er_b1[b * 128 + t];
      else if (t >= 384) v = diss_b[b * 128 + (t - 384)];
      bp512[b * 512 + t] = v;
    } else {
      t2 -= 3 * 512;
      const int b = t2 >> 8, t = t2 & 255;
      bfd[b * 256 + t] = (t < 128) ? 0.f : diss_b[b * 128 + (t - 128)];
    }
    return;
  }
  const float* src;
  size_t soff;
  if (idx < 16384) {
    src = emb_w; soff = idx;
  } else if (idx < 24576) {
    src = ro_w; soff = idx - 16384;
  } else {
    int t = idx - 24576;
    const int b = t / 98304;
    t -= b * 98304;
    if (t < 32768) {  // Wp: rows<128 -> er_w1 cols 0-127; rows>=128 -> cols 128-255
      const int r = t >> 7, c = t & 127;
      src = er_w1 + (size_t)b * 32768;
      soff = (r < 128) ? ((size_t)r * 256 + c) : ((size_t)(r - 128) * 256 + 128 + c);
    } else if (t < 65536) {  // Wfd: rows<128 lap, rows>=128 diss
      const int u = t - 32768;
      if (u < 16384) { src = lap_w + (size_t)b * 16384; soff = u; }
      else { src = diss_w + (size_t)b * 16384; soff = u - 16384; }
    } else if (t < 81920) {
      src = mlp_w1 + (size_t)b * 16384; soff = t - 65536;
    } else {
      src = mlp_w2 + (size_t)b * 16384; soff = t - 81920;
    }
  }
  wb[idx] = f2b(src[soff]);
}

// ---------------------------------------------------------------------------
// Edge resistance, dst-sorted, fp8 P tables. 2 edges per 16-lane group,
// all 4 row-gathers issued up front; shared 4-level shfl ladder.
// ---------------------------------------------------------------------------
__global__ __launch_bounds__(256) void edge_r_k(
    const uint2* __restrict__ P1, const uint2* __restrict__ P2,
    const int* __restrict__ ss, const int* __restrict__ ds,
    const float* __restrict__ w2, const float* __restrict__ b2,
    float* __restrict__ r_out, float* __restrict__ deg) {
  const int tid = threadIdx.x;
  const int sub = tid & 15;
  const size_t e0 = (size_t)blockIdx.x * 32 + (tid >> 4) * 2;
  const size_t e1 = e0 + 1;
  const float4 w0 = *(const float4*)(w2 + sub * 8);
  const float4 w1 = *(const float4*)(w2 + sub * 8 + 4);
  const int s0 = ss[e0], s1 = ss[e1];
  const int d0 = ds[e0], d1 = ds[e1];
  const uint2 av0 = P1[(size_t)s0 * 16 + sub];
  const uint2 cv0 = P2[(size_t)d0 * 16 + sub];
  const uint2 av1 = P1[(size_t)s1 * 16 + sub];
  const uint2 cv1 = P2[(size_t)d1 * 16 + sub];

  v2f a0 = dec_lo(av0.x), a1 = dec_hi(av0.x), a2 = dec_lo(av0.y),
      a3 = dec_hi(av0.y);
  v2f c0 = dec_lo(cv0.x), c1 = dec_hi(cv0.x), c2 = dec_lo(cv0.y),
      c3 = dec_hi(cv0.y);
  float sum0 = fmaxf(a0.x + c0.x, 0.f) * w0.x;
  sum0 = fmaf(fmaxf(a0.y + c0.y, 0.f), w0.y, sum0);
  sum0 = fmaf(fmaxf(a1.x + c1.x, 0.f), w0.z, sum0);
  sum0 = fmaf(fmaxf(a1.y + c1.y, 0.f), w0.w, sum0);
  sum0 = fmaf(fmaxf(a2.x + c2.x, 0.f), w1.x, sum0);
  sum0 = fmaf(fmaxf(a2.y + c2.y, 0.f), w1.y, sum0);
  sum0 = fmaf(fmaxf(a3.x + c3.x, 0.f), w1.z, sum0);
  sum0 = fmaf(fmaxf(a3.y + c3.y, 0.f), w1.w, sum0);

  a0 = dec_lo(av1.x); a1 = dec_hi(av1.x); a2 = dec_lo(av1.y);
  a3 = dec_hi(av1.y);
  c0 = dec_lo(cv1.x); c1 = dec_hi(cv1.x); c2 = dec_lo(cv1.y);
  c3 = dec_hi(cv1.y);
  float sum1 = fmaxf(a0.x + c0.x, 0.f) * w0.x;
  sum1 = fmaf(fmaxf(a0.y + c0.y, 0.f), w0.y, sum1);
  sum1 = fmaf(fmaxf(a1.x + c1.x, 0.f), w0.z, sum1);
  sum1 = fmaf(fmaxf(a1.y + c1.y, 0.f), w0.w, sum1);
  sum1 = fmaf(fmaxf(a2.x + c2.x, 0.f), w1.x, sum1);
  sum1 = fmaf(fmaxf(a2.y + c2.y, 0.f), w1.y, sum1);
  sum1 = fmaf(fmaxf(a3.x + c3.x, 0.f), w1.z, sum1);
  sum1 = fmaf(fmaxf(a3.y + c3.y, 0.f), w1.w, sum1);

#pragma unroll
  for (int off = 8; off > 0; off >>= 1) {
    sum0 += __shfl_xor(sum0, off);
    sum1 += __shfl_xor(sum1, off);
  }
  if (sub == 0) {
    const float rv0 = fabsf(sum0 + b2[0]);
    const float rv1 = fabsf(sum1 + b2[0]);
    r_out[e0] = rv0;
    r_out[e1] = rv1;
    atomicAdd(&deg[s0], rv0);
    atomicAdd(&deg[s1], rv1);
  }
}

// ---------------------------------------------------------------------------
// CSR build (by dst): hist -> parallel scan -> sorted src/dst arrays.
// ---------------------------------------------------------------------------
constexpr int NSC = (N_ + 1023) / 1024;  // 49

__global__ void hist_k(const int* __restrict__ dst, int* __restrict__ cnt) {
  const int e = blockIdx.x * 256 + threadIdx.x;
  if (e < E_) atomicAdd(&cnt[dst[e]], 1);
}

__global__ __launch_bounds__(1024) void partial_k(const int* __restrict__ cnt,
                                                  int* __restrict__ psum) {
  __shared__ int sm[1024];
  const int tid = threadIdx.x;
  const int i = blockIdx.x * 1024 + tid;
  sm[tid] = (i < N_) ? cnt[i] : 0;
  __syncthreads();
  for (int off = 512; off > 0; off >>= 1) {
    if (tid < off) sm[tid] += sm[tid + off];
    __syncthreads();
  }
  if (tid == 0) psum[blockIdx.x] = sm[0];
}

__global__ __launch_bounds__(64) void scanp_k(int* __restrict__ psum) {
  const int tid = threadIdx.x;
  int v = (tid < NSC) ? psum[tid] : 0;
  const int orig = v;
#pragma unroll
  for (int off = 1; off < 64; off <<= 1) {
    const int u = __shfl_up(v, off);
    if (tid >= off) v += u;
  }
  if (tid < NSC) psum[tid] = v - orig;  // exclusive
}

__global__ __launch_bounds__(1024) void rowptr_k(const int* __restrict__ cnt,
                                                 const int* __restrict__ psum,
                                                 int* __restrict__ rowptr,
                                                 int* __restrict__ cursor) {
  __shared__ int sm[1024];
  const int tid = threadIdx.x;
  const int i = blockIdx.x * 1024 + tid;
  const int orig = (i < N_) ? cnt[i] : 0;
  sm[tid] = orig;
  __syncthreads();
  for (int off = 1; off < 1024; off <<= 1) {
    const int mine = sm[tid];
    const int u = (tid >= off) ? sm[tid - off] : 0;
    __syncthreads();
    sm[tid] = mine + u;
    __syncthreads();
  }
  const int excl = sm[tid] - orig + psum[blockIdx.x];
  if (i < N_) {
    rowptr[i] = excl;
    cursor[i] = excl;
  }
  if (i == 0) rowptr[N_] = E_;
}

__global__ void permute_k(const int* __restrict__ src,
                          const int* __restrict__ dst, int* __restrict__ cursor,
                          int* __restrict__ ss, int* __restrict__ ds) {
  const int e = blockIdx.x * 256 + threadIdx.x;
  if (e < E_) {
    const int d = dst[e];
    const int p = atomicAdd(&cursor[d], 1);
    ss[p] = src[e];
    ds[p] = d;
  }
}

// ---------------------------------------------------------------------------
// Fused aggregate + update. f/diss fp8 (128 B rows), xb/vb bf16.
// One wave per node; 8-deep unrolled gather volley (latency cover).
// ---------------------------------------------------------------------------
template <bool FIRST>
__global__ __launch_bounds__(256) void agg_update_k(
    unsigned int* __restrict__ xb, unsigned int* __restrict__ vb,
    const u16* __restrict__ f8, const u16* __restrict__ diss8,
    const float* __restrict__ deg, const float* __restrict__ r,
    const int* __restrict__ ss, const int* __restrict__ rowptr) {
  const int wid = threadIdx.x >> 6;
  const int lane = threadIdx.x & 63;
  const int n = blockIdx.x * 4 + wid;
  const int beg = rowptr[n];
  const int end = rowptr[n + 1];
  float ax = 0.f, ay = 0.f;
  for (int i = beg; i < end; i += 8) {
    int ei[8];
    float rr[8];
    unsigned int fv[8];
#pragma unroll
    for (int k = 0; k < 8; ++k) ei[k] = (i + k < end) ? i + k : i;
#pragma unroll
    for (int k = 0; k < 8; ++k) {
      const int s = NT_LOAD(ss + ei[k]);
      fv[k] = f8[(size_t)s * 64 + lane];
    }
#pragma unroll
    for (int k = 0; k < 8; ++k)
      rr[k] = (i + k < end) ? NT_LOAD(r + ei[k]) : 0.f;
#pragma unroll
    for (int k = 0; k < 8; ++k) {
      const v2f dd = dec_lo(fv[k]);
      ax = fmaf(rr[k], dd.x, ax);
      ay = fmaf(rr[k], dd.y, ay);
    }
  }
  const size_t idx = (size_t)n * 64 + lane;
  const v2f fn = dec_lo((unsigned int)f8[idx]);
  const float dg = deg[n];
  const float cx = dg * fn.x - ax;
  const float cy = dg * fn.y - ay;
  float vx, vy;
  if (FIRST) {
    vx = -EPS_ * cx;
    vy = -EPS_ * cy;
    vb[idx] = pk(vx, vy);
  } else {
    const v2f dsv = dec_lo((unsigned int)diss8[idx]);
    const unsigned int vv = vb[idx];
    vx = b2f((u16)(vv & 0xffffu));
    vy = b2f((u16)(vv >> 16));
    vx = vx - EPS_ * (cx + dsv.x * vx);
    vy = vy - EPS_ * (cy + dsv.y * vy);
  }
  const unsigned int xv = xb[idx];
  const float nx = b2f((u16)(xv & 0xffffu)) + EPS_ * vx;
  const float ny = b2f((u16)(xv >> 16)) + EPS_ * vy;
  xb[idx] = pk(nx, ny);
}

extern "C" void kernel_launch(void* const* d_in, const int* in_sizes, int n_in,
                              void* d_out, int out_size, void* d_ws,
                              size_t ws_size, hipStream_t stream) {
  const float* x_in = (const float*)d_in[0];
  const int* ei = (const int*)d_in[1];
  const int* src = ei;
  const int* dst = ei + E_;
  const float* emb_w = (const float*)d_in[2];
  const float* emb_b = (const float*)d_in[3];
  const float* lap_w = (const float*)d_in[4];
  const float* er_w1 = (const float*)d_in[5];
  const float* er_b1 = (const float*)d_in[6];
  const float* er_w2 = (const float*)d_in[7];
  const float* er_b2 = (const float*)d_in[8];
  const float* diss_w = (const float*)d_in[9];
  const float* diss_b = (const float*)d_in[10];
  const float* mlp_w1 = (const float*)d_in[11];
  const float* mlp_b1 = (const float*)d_in[12];
  const float* mlp_w2 = (const float*)d_in[13];
  const float* mlp_b2 = (const float*)d_in[14];
  const float* ro_w = (const float*)d_in[15];
  const float* ro_b = (const float*)d_in[16];
  float* out = (float*)d_out;

  // workspace layout
  const size_t NF = (size_t)N_ * H_;
  u16* xb = (u16*)d_ws;             // NF bf16 (x state)
  u16* vb = xb + NF;                // NF bf16 (v)
  u8* P1 = (u8*)(vb + NF);          // NF fp8
  u8* P2 = P1 + NF;                 // NF fp8
  u8* F8 = P2 + NF;                 // NF fp8
  u8* D8 = F8 + NF;                 // NF fp8
  float* r = (float*)(D8 + NF);     // E (dst-sorted)
  float* deg = r + E_;              // N
  int* rowptr = (int*)(deg + N_);   // N+1
  int* cursor = rowptr + (N_ + 1);  // N
  int* ss = cursor + N_;            // E (src, dst-sorted)
  int* ds = ss + E_;                // E (dst, dst-sorted)
  int* psum = ds + E_;              // NSC
  u16* wb = (u16*)(psum + NSC);     // WB_TOTAL bf16
  float* bp512 = (float*)(wb + WB_TOTAL + (WB_TOTAL & 1));  // 3*512
  float* bfd = bp512 + 3 * 512;     // 3*256

  const int g64 = (N_ + 63) / 64;  // 782
  const int e_grid = (E_ + 255) / 256;

  // pack weights + biases (merged)
  convall_k<<<(CONV_TOT + 255) / 256, 256, 0, stream>>>(
      emb_w, ro_w, er_w1, lap_w, diss_w, mlp_w1, mlp_w2, er_b1, diss_b, wb,
      bp512, bfd);

  // CSR by dst (topology fixed for whole launch)
  hipMemsetAsync(cursor, 0, N_ * sizeof(int), stream);
  hist_k<<<e_grid, 256, 0, stream>>>(dst, cursor);
  partial_k<<<NSC, 1024, 0, stream>>>(cursor, psum);
  scanp_k<<<1, 64, 0, stream>>>(psum);
  rowptr_k<<<NSC, 1024, 0, stream>>>(cursor, psum, rowptr, cursor);
  permute_k<<<e_grid, 256, 0, stream>>>(src, dst, cursor, ss, ds);

  // xb = emb(x_in)  (fp32 A input, bf16 out, 1 group)
  gemm_k<1, 4, 1, 0, 0, 0, 0, 0><<<g64, 256, 0, stream>>>(
      x_in, wb + WB_EMB, emb_b, xb, nullptr, nullptr, nullptr);

  for (int b = 0; b < B_; ++b) {
    const u16* Wp = wb + WB_BLK + (size_t)b * 98304;   // 256 rows (er split)
    const u16* Wfd = Wp + 32768;                       // 256 rows (lap;diss)
    const u16* Wm1 = Wfd + 32768;
    const u16* Wm2 = Wm1 + 16384;
    const float* b2 = er_b2 + b;
    const float* w2 = er_w2 + (size_t)b * H_;

    // Merged it=0 GEMM: [P1 | P2 | f | diss] = xb @ [Wp;Wfd]^T (4 groups).
    gemm_k<4, 4, 0, 1, 0, 0, 0, 1><<<g64, 256, 0, stream>>>(
        xb, Wp, bp512 + b * 512, P1, P2, F8, D8);
    hipMemsetAsync(deg, 0, N_ * sizeof(float), stream);
    edge_r_k<<<E_ / 32, 256, 0, stream>>>((const uint2*)P1, (const uint2*)P2,
                                          ss, ds, w2, b2, r, deg);

    // it = 0 (uses F8/D8 from merged GEMM)
    agg_update_k<true><<<N_ / 4, 256, 0, stream>>>(
        (unsigned int*)xb, (unsigned int*)vb, (const u16*)F8, (const u16*)D8,
        deg, r, ss, rowptr);
    // it = 1: recompute f/diss from updated xb (2 groups)
    gemm_k<2, 4, 0, 1, 0, 1, 0, 0><<<g64, 256, 0, stream>>>(
        xb, Wfd, bfd + b * 256, F8, D8, nullptr, nullptr);
    agg_update_k<false><<<N_ / 4, 256, 0, stream>>>(
        (unsigned int*)xb, (unsigned int*)vb, (const u16*)F8, (const u16*)D8,
        deg, r, ss, rowptr);

    // xb = tanh(xb@Wm1^T + bm1) @ Wm2^T + bm2
    mlp6_k<<<g64, 256, 0, stream>>>(xb, Wm1, mlp_b1 + b * H_, Wm2,
                                    mlp_b2 + b * H_, xb);
  }
  gemm_k<1, 2, 0, 2, 0, 0, 0, 0><<<g64, 128, 0, stream>>>(
      xb, wb + WB_RO, ro_b, out, nullptr, nullptr, nullptr);
}